// Round 7
// baseline (160.106 us; speedup 1.0000x reference)
//
#include <hip/hip_runtime.h>
#include <math.h>

typedef __attribute__((ext_vector_type(8))) short bf16x8;
typedef _Float16 f16x8 __attribute__((ext_vector_type(8)));
typedef __attribute__((ext_vector_type(4))) float f32x4;

#define PI_F 3.14159265358979323846f

__device__ __forceinline__ unsigned short f2bf(float f) {
  unsigned int u = __float_as_uint(f);
  u += 0x7FFFu + ((u >> 16) & 1u);   // RNE to bf16
  return (unsigned short)(u >> 16);
}

__device__ __forceinline__ float bf2f(unsigned short u) {
  return __uint_as_float(((unsigned int)u) << 16);
}

__device__ __forceinline__ void async_ld16(const unsigned short* g, unsigned short* l) {
  __builtin_amdgcn_global_load_lds(
      (const __attribute__((address_space(1))) void*)g,
      (__attribute__((address_space(3))) void*)l,
      16, 0, 0);
}

// fast erf, A&S 7.1.26, |err| <= 1.5e-7 absolute
__device__ __forceinline__ float fast_erf(float x) {
  float a = fabsf(x);
  float t = 1.0f / fmaf(0.3275911f, a, 1.0f);
  float p = t * fmaf(t, fmaf(t, fmaf(t, fmaf(t, 1.061405429f, -1.453152027f),
                                     1.421413741f), -0.284496736f), 0.254829592f);
  float e = __expf(-a * a);
  float r = 1.0f - p * e;
  return copysignf(r, x);
}

__device__ __forceinline__ float fast_tanh(float a) {
  float e = __expf(2.0f * a);
  return 1.0f - 2.0f / (e + 1.0f);
}

// RX on stored basis: XOR-pair (lane-mask ML, register-mask MR); RX matrix symmetric.
template<int ML, int MR>
__device__ __forceinline__ void apply_rx(float re[4], float im[4], float c, float s) {
  float pr[4], pi[4];
  #pragma unroll
  for (int r = 0; r < 4; r++) {
    float vr = re[r ^ MR], vi = im[r ^ MR];
    if (ML) { vr = __shfl_xor(vr, ML, 64); vi = __shfl_xor(vi, ML, 64); }
    pr[r] = vr; pi[r] = vi;
  }
  #pragma unroll
  for (int r = 0; r < 4; r++) {
    re[r] = fmaf(c, re[r],  s * pi[r]);
    im[r] = fmaf(c, im[r], -s * pr[r]);
  }
}

// fold-reduce 8 values across 64 lanes: 10 shuffles. On exit v[0] of lane L holds
// the wave-sum of value w(L) = 4*(L&1) + (L&2) + ((L>>2)&1).
__device__ __forceinline__ void fold_reduce8(float v[8], int L) {
  #pragma unroll
  for (int step = 0; step < 3; step++) {
    int d = 1 << step;
    int half = 4 >> step;
    bool hi = (L & d) != 0;
    #pragma unroll
    for (int w = 0; w < half; w++) {
      float send = hi ? v[w] : v[w + half];
      float recv = __shfl_xor(send, d, 64);
      v[w] = (hi ? v[w + half] : v[w]) + recv;
    }
  }
  v[0] += __shfl_xor(v[0], 8, 64);
  v[0] += __shfl_xor(v[0], 16, 64);
  v[0] += __shfl_xor(v[0], 32, 64);
}

// ---------------- prep: adj/Wg cvt, U-builder (interleaved), G-builder, x transpose ----
// blocks [0,1024): adj cvt; [1024,1088): Wg cvt; [1088,1152): U-builder;
// [1152,1168): G-builder; [1168,5264): x transpose (16,1024,256)->(4096,1024) bf16.
__global__ __launch_bounds__(256)
void prep_kernel(const float* __restrict__ adj, unsigned short* __restrict__ adj_bf,
                 const float* __restrict__ Wg, unsigned short* __restrict__ Wg_bf,
                 const float* __restrict__ qw, unsigned short* __restrict__ Uri,
                 const float* __restrict__ Wpost, _Float16* __restrict__ Gt,
                 const float* __restrict__ x, unsigned short* __restrict__ xT) {
  __shared__ float smem[1056];
  int bid = blockIdx.x, t = threadIdx.x;
  if (bid < 1024) {
    int i = bid * 256 + t;
    float4 v = ((const float4*)adj)[i];
    ushort4 o; o.x = f2bf(v.x); o.y = f2bf(v.y); o.z = f2bf(v.z); o.w = f2bf(v.w);
    ((ushort4*)adj_bf)[i] = o;
  } else if (bid < 1088) {
    int i = (bid - 1024) * 256 + t;
    float4 v = ((const float4*)Wg)[i];
    ushort4 o; o.x = f2bf(v.x); o.y = f2bf(v.y); o.z = f2bf(v.z); o.w = f2bf(v.w);
    ((ushort4*)Wg_bf)[i] = o;
  } else if (bid < 1152) {
    // U-builder: simulate entangler on basis k. CNOT rings deferred (linear maps);
    // layer-2 RX masks = R^-1 e_w; logical index n = R^2 s (rows of R^2 below).
    // Output layout INTERLEAVED by 16-blocks: row (n>>4)*32 + (n&15)      = Ure[n][*]
    //                                         row (n>>4)*32 + 16 + (n&15) = Uim[n][*]
    if (t < 16) { smem[t] = cosf(0.5f * qw[t]); smem[16 + t] = sinf(0.5f * qw[t]); }
    __syncthreads();
    int wv = t >> 6, L = t & 63;
    int k = (bid - 1088) * 4 + wv;
    float re[4], im[4];
    #pragma unroll
    for (int r = 0; r < 4; r++) { re[r] = (r * 64 + L == k) ? 1.f : 0.f; im[r] = 0.f; }
    // layer 1 RX (F = I)
    apply_rx<1, 0>(re, im, smem[0], smem[16]);
    apply_rx<2, 0>(re, im, smem[1], smem[17]);
    apply_rx<4, 0>(re, im, smem[2], smem[18]);
    apply_rx<8, 0>(re, im, smem[3], smem[19]);
    apply_rx<16, 0>(re, im, smem[4], smem[20]);
    apply_rx<32, 0>(re, im, smem[5], smem[21]);
    apply_rx<0, 1>(re, im, smem[6], smem[22]);
    apply_rx<0, 2>(re, im, smem[7], smem[23]);
    // layer 2 RX (F = R): masks R^-1 e_w
    apply_rx<3, 0>(re, im, smem[8], smem[24]);
    apply_rx<6, 0>(re, im, smem[9], smem[25]);
    apply_rx<12, 0>(re, im, smem[10], smem[26]);
    apply_rx<24, 0>(re, im, smem[11], smem[27]);
    apply_rx<48, 0>(re, im, smem[12], smem[28]);
    apply_rx<32, 1>(re, im, smem[13], smem[29]);
    apply_rx<0, 3>(re, im, smem[14], smem[30]);
    apply_rx<3, 2>(re, im, smem[15], smem[31]);
    const int M[8] = {0xAB, 0xFD, 0xFA, 0xF5, 0xEA, 0xD5, 0xAA, 0x55};
    #pragma unroll
    for (int r = 0; r < 4; r++) {
      int n = 0;
      #pragma unroll
      for (int w = 0; w < 8; w++) {
        int bit = (__popc(L & (M[w] & 63)) ^ __popc((r << 6) & M[w])) & 1;
        n |= bit << w;
      }
      int row_re = ((n >> 4) << 5) + (n & 15);
      Uri[(size_t)row_re * 256 + k] = f2bf(re[r]);
      Uri[(size_t)(row_re + 16) * 256 + k] = f2bf(im[r]);
    }
  } else if (bid < 1168) {
    // G-builder: Gt[h][n] = sum_w (-1)^{bit_w(n)} Wpost[h][w]  (f16)
    int tid = (bid - 1152) * 256 + t;   // [0,4096)
    int h = tid >> 4;
    int n0 = (tid & 15) << 4;
    float wv8[8];
    #pragma unroll
    for (int w = 0; w < 8; w++) wv8[w] = Wpost[h * 8 + w];
    #pragma unroll
    for (int j = 0; j < 16; j++) {
      int n = n0 + j;
      float sum = 0.f;
      #pragma unroll
      for (int w = 0; w < 8; w++) sum += ((n >> w) & 1) ? -wv8[w] : wv8[w];
      Gt[h * 256 + n] = (_Float16)sum;
    }
  } else {
    int tb = bid - 1168;
    int jt = tb & 31, ht = (tb >> 5) & 7, bb = tb >> 8;
    int tx = t & 31, ty = t >> 5;
    const float* xb = x + (size_t)bb * 1024 * 256;
    #pragma unroll
    for (int i = 0; i < 4; i++) {
      int j = jt * 32 + ty + i * 8;
      smem[(ty + i * 8) * 33 + tx] = xb[(size_t)j * 256 + ht * 32 + tx];
    }
    __syncthreads();
    unsigned short* xTb = xT + (size_t)bb * 256 * 1024;
    #pragma unroll
    for (int i = 0; i < 4; i++) {
      int h = ht * 32 + ty + i * 8;
      xTb[(size_t)h * 1024 + jt * 32 + tx] = f2bf(smem[tx * 33 + ty + i * 8]);
    }
  }
}

// ---------------- MFMA GEMM, C = A * Bt^T, tile 128(M) x 64(N) x 32(K) ----
// MODE 0: bf16 inputs, store bf16 C.
// MODE 1: bf16 inputs, bias + GELU(erf), store bf16 C.
// MODE 2: bf16 inputs (P0 x Uri^T, Uri re/im interleaved by 16-blocks);
//         epilogue T = acc_re^2 + acc_im^2, store f16 T (N cols -> 256 T cols).
// MODE 3: f16 inputs (T x Gt^T), bias, store fp32 with sample un-permute
//         (row s = i*16+b -> out row b*1024+i).
template<int MODE>
__global__ __launch_bounds__(256)
void gemm_bt_kernel(const unsigned short* __restrict__ A,
                    const unsigned short* __restrict__ Bt,
                    void* __restrict__ C,
                    const float* __restrict__ bias,
                    int K, int tilesM, int tilesN, int ldC) {
  __shared__ unsigned short As[128 * 32];
  __shared__ unsigned short Bs[64 * 32];
  int rr  = blockIdx.x;
  int im  = rr / tilesN;
  int in_ = rr % tilesN;
  const unsigned short* Ab  = A  + (long long)im * 128 * K;
  const unsigned short* Btb = Bt + (long long)in_ * 64 * K;

  int t = threadIdx.x;
  int wv = t >> 6, lane = t & 63;
  int wm = wv >> 1, wn = wv & 1;
  int l15 = lane & 15, quad = lane >> 4;
  int row0 = t >> 2, cg = t & 3;

  f32x4 acc[4][2] = {};

  for (int kk = 0; kk < K; kk += 32) {
    __syncthreads();
    #pragma unroll
    for (int q = 0; q < 2; q++) {
      int row = row0 + q * 64;
      async_ld16(Ab + (long long)row * K + kk + cg * 8,
                 &As[(wv * 16 + q * 64) * 32]);
    }
    async_ld16(Btb + (long long)row0 * K + kk + cg * 8,
               &Bs[wv * 16 * 32]);
    __syncthreads();
    if constexpr (MODE == 3) {
      f16x8 af[4], bfr[2];
      #pragma unroll
      for (int mt = 0; mt < 4; mt++)
        af[mt] = *(const f16x8*)&As[(wm * 64 + mt * 16 + l15) * 32 + quad * 8];
      #pragma unroll
      for (int nt = 0; nt < 2; nt++)
        bfr[nt] = *(const f16x8*)&Bs[(wn * 32 + nt * 16 + l15) * 32 + quad * 8];
      #pragma unroll
      for (int mt = 0; mt < 4; mt++)
        #pragma unroll
        for (int nt = 0; nt < 2; nt++)
          acc[mt][nt] = __builtin_amdgcn_mfma_f32_16x16x32_f16(af[mt], bfr[nt], acc[mt][nt], 0, 0, 0);
    } else {
      bf16x8 af[4], bfr[2];
      #pragma unroll
      for (int mt = 0; mt < 4; mt++)
        af[mt] = *(const bf16x8*)&As[(wm * 64 + mt * 16 + l15) * 32 + quad * 8];
      #pragma unroll
      for (int nt = 0; nt < 2; nt++)
        bfr[nt] = *(const bf16x8*)&Bs[(wn * 32 + nt * 16 + l15) * 32 + quad * 8];
      #pragma unroll
      for (int mt = 0; mt < 4; mt++)
        #pragma unroll
        for (int nt = 0; nt < 2; nt++)
          acc[mt][nt] = __builtin_amdgcn_mfma_f32_16x16x32_bf16(af[mt], bfr[nt], acc[mt][nt], 0, 0, 0);
    }
  }

  if constexpr (MODE == 2) {
    // T[s][n]: n = (in_*2 + wn)*16 + l15 ; value = acc[mt][0]^2 + acc[mt][1]^2
    _Float16* Tb = (_Float16*)C;
    int ncol = (in_ * 2 + wn) * 16 + l15;
    #pragma unroll
    for (int mt = 0; mt < 4; mt++) {
      #pragma unroll
      for (int r = 0; r < 4; r++) {
        int rowg = im * 128 + wm * 64 + mt * 16 + quad * 4 + r;
        float tv = acc[mt][0][r] * acc[mt][0][r] + acc[mt][1][r] * acc[mt][1][r];
        Tb[(size_t)rowg * ldC + ncol] = (_Float16)tv;
      }
    }
  } else {
    int n0 = in_ * 64;
    #pragma unroll
    for (int mt = 0; mt < 4; mt++) {
      #pragma unroll
      for (int nt = 0; nt < 2; nt++) {
        int colg = n0 + wn * 32 + nt * 16 + l15;
        #pragma unroll
        for (int r = 0; r < 4; r++) {
          int rowg = im * 128 + wm * 64 + mt * 16 + quad * 4 + r;
          float v = acc[mt][nt][r];
          if constexpr (MODE == 0) {
            ((unsigned short*)C)[(size_t)rowg * ldC + colg] = f2bf(v);
          } else if constexpr (MODE == 1) {
            v += bias[colg];
            v = 0.5f * v * (1.0f + fast_erf(v * 0.7071067811865475f));
            ((unsigned short*)C)[(size_t)rowg * ldC + colg] = f2bf(v);
          } else {  // MODE 3
            v += bias[colg];
            int orow = (rowg & 15) * 1024 + (rowg >> 4);   // s=i*16+b -> b*1024+i
            ((float*)C)[(size_t)orow * ldC + colg] = v;
          }
        }
      }
    }
  }
}

// ---------------- P0-builder: angles -> RY product state (bf16, logical basis) ----
// one sample per wave; lane L writes entries n = 4L..4L+3 (n bit w <-> wire w).
__global__ __launch_bounds__(256)
void p0_builder_kernel(const unsigned short* __restrict__ g,
                       const float* __restrict__ Wpre, const float* __restrict__ bpre,
                       unsigned short* __restrict__ P0) {
  __shared__ float sWpre[2048];   // [w][h]  8x256
  int t = threadIdx.x;
  for (int i = t; i < 2048; i += 256) sWpre[i] = Wpre[i];
  __syncthreads();

  int wv = t >> 6, L = t & 63;
  long long s = (long long)blockIdx.x * 4 + wv;
  ushort4 gu = ((const ushort4*)(g + s * 256))[L];
  float g0 = bf2f(gu.x), g1 = bf2f(gu.y), g2 = bf2f(gu.z), g3 = bf2f(gu.w);

  float ang[8];
  #pragma unroll
  for (int w = 0; w < 8; w++) {
    float4 wp = *(const float4*)&sWpre[w * 256 + 4 * L];
    float a = g0 * wp.x;
    a = fmaf(g1, wp.y, a);
    a = fmaf(g2, wp.z, a);
    a = fmaf(g3, wp.w, a);
    ang[w] = a;
  }
  fold_reduce8(ang, L);
  float angf[8];
  #pragma unroll
  for (int w = 0; w < 8; w++) {
    int src = ((w >> 2) & 1) | (w & 2) | ((w & 1) << 2);
    angf[w] = __shfl(ang[0], src, 64);
  }

  float cw[8], sw[8];
  #pragma unroll
  for (int w = 0; w < 8; w++) {
    float th = (0.5f * PI_F) * fast_tanh(angf[w] + bpre[w]);
    cw[w] = __cosf(th); sw[w] = __sinf(th);
  }

  // amp index n = 4*L + j : bits 0,1 = j ; bits 2..7 = lane bits 0..5
  float pl = 1.f;
  #pragma unroll
  for (int bbit = 0; bbit < 6; bbit++) pl *= ((L >> bbit) & 1) ? sw[bbit + 2] : cw[bbit + 2];
  ushort4 o;
  o.x = f2bf(pl * cw[0] * cw[1]);
  o.y = f2bf(pl * sw[0] * cw[1]);
  o.z = f2bf(pl * cw[0] * sw[1]);
  o.w = f2bf(pl * sw[0] * sw[1]);
  ((ushort4*)(P0 + s * 256))[L] = o;
}

// ---------------- host launch ----------------
extern "C" void kernel_launch(void* const* d_in, const int* in_sizes, int n_in,
                              void* d_out, int out_size, void* d_ws, size_t ws_size,
                              hipStream_t stream) {
  const float* x     = (const float*)d_in[0];  // (16,1024,256)
  const float* adj   = (const float*)d_in[1];  // (1024,1024)
  const float* Wg    = (const float*)d_in[2];  // (256,256)
  const float* bg    = (const float*)d_in[3];  // (256,)
  const float* Wpre  = (const float*)d_in[4];  // (8,256)
  const float* bpre  = (const float*)d_in[5];  // (8,)
  const float* qw    = (const float*)d_in[6];  // (2,8)
  const float* Wpost = (const float*)d_in[7];  // (256,8)
  const float* bpost = (const float*)d_in[8];  // (256,)
  float* out = (float*)d_out;                  // (16,1024,256)

  char* ws = (char*)d_ws;
  unsigned short* adj_bf  = (unsigned short*)(ws + 0);          // 2 MiB
  unsigned short* Wg_bf   = (unsigned short*)(ws + 2097152);    // 128 KiB
  unsigned short* xT_bf   = (unsigned short*)(ws + 2228224);    // 8 MiB  (4096 x 1024)
  unsigned short* xagg_bf = (unsigned short*)(ws + 10616832);   // 8 MiB  (1024 x 4096)
  unsigned short* g_bf    = (unsigned short*)(ws + 19005440);   // 8 MiB  (16384 x 256)
  unsigned short* P0      = (unsigned short*)(ws + 27394048);   // 8 MiB  (16384 x 256)
  unsigned short* Uri     = (unsigned short*)(ws + 35782656);   // 256 KiB (512 x 256)
  _Float16*       Gt      = (_Float16*)(ws + 36044800);         // 128 KiB (256 x 256)
  _Float16*       Tbuf    = (_Float16*)(ws + 36175872);         // 8 MiB  (16384 x 256)

  // 1) prep: adj/Wg cvt + U-builder (interleaved) + G-builder + x transpose
  prep_kernel<<<5264, 256, 0, stream>>>(adj, adj_bf, Wg, Wg_bf, qw, Uri,
                                        Wpost, Gt, x, xT_bf);

  // 2) xagg = adj @ X'  (single GEMM 1024 x 4096 x 1024) -> bf16, layout [i][b*256+h]
  gemm_bt_kernel<0><<<512, 256, 0, stream>>>(adj_bf, xT_bf, (void*)xagg_bf, nullptr,
                                             1024, 8, 64, 4096);

  // 3) g = gelu(xagg @ Wg^T + bg) -> bf16 (rows are samples s = i*16+b)
  gemm_bt_kernel<1><<<512, 256, 0, stream>>>(xagg_bf, Wg_bf, (void*)g_bf, bg,
                                             256, 128, 4, 256);

  // 4) P0 = RY product state per sample (bf16, logical basis)
  p0_builder_kernel<<<4096, 256, 0, stream>>>(g_bf, Wpre, bpre, P0);

  // 5) S = P0 @ Uri^T, fused T = |S|^2 epilogue -> f16 (16384 x 256)
  gemm_bt_kernel<2><<<1024, 256, 0, stream>>>(P0, Uri, (void*)Tbuf, nullptr,
                                              256, 128, 8, 256);

  // 6) out = T @ Gt^T + bpost -> fp32, un-permuted rows
  gemm_bt_kernel<3><<<512, 256, 0, stream>>>((const unsigned short*)Tbuf,
                                             (const unsigned short*)Gt, (void*)out, bpost,
                                             256, 128, 4, 256);
}

// Round 8
// 154.773 us; speedup vs baseline: 1.0345x; 1.0345x over previous
//
#include <hip/hip_runtime.h>
#include <math.h>

typedef __attribute__((ext_vector_type(8))) short bf16x8;
typedef _Float16 f16x8 __attribute__((ext_vector_type(8)));
typedef __attribute__((ext_vector_type(4))) float f32x4;

#define PI_F 3.14159265358979323846f

__device__ __forceinline__ unsigned short f2bf(float f) {
  unsigned int u = __float_as_uint(f);
  u += 0x7FFFu + ((u >> 16) & 1u);   // RNE to bf16
  return (unsigned short)(u >> 16);
}

__device__ __forceinline__ float bf2f(unsigned short u) {
  return __uint_as_float(((unsigned int)u) << 16);
}

__device__ __forceinline__ void async_ld16(const unsigned short* g, unsigned short* l) {
  __builtin_amdgcn_global_load_lds(
      (const __attribute__((address_space(1))) void*)g,
      (__attribute__((address_space(3))) void*)l,
      16, 0, 0);
}

// fast erf, A&S 7.1.26, |err| <= 1.5e-7 absolute
__device__ __forceinline__ float fast_erf(float x) {
  float a = fabsf(x);
  float t = 1.0f / fmaf(0.3275911f, a, 1.0f);
  float p = t * fmaf(t, fmaf(t, fmaf(t, fmaf(t, 1.061405429f, -1.453152027f),
                                     1.421413741f), -0.284496736f), 0.254829592f);
  float e = __expf(-a * a);
  float r = 1.0f - p * e;
  return copysignf(r, x);
}

__device__ __forceinline__ float fast_tanh(float a) {
  float e = __expf(2.0f * a);
  return 1.0f - 2.0f / (e + 1.0f);
}

// RX on stored basis: XOR-pair (lane-mask ML, register-mask MR); RX matrix symmetric.
template<int ML, int MR>
__device__ __forceinline__ void apply_rx(float re[4], float im[4], float c, float s) {
  float pr[4], pi[4];
  #pragma unroll
  for (int r = 0; r < 4; r++) {
    float vr = re[r ^ MR], vi = im[r ^ MR];
    if (ML) { vr = __shfl_xor(vr, ML, 64); vi = __shfl_xor(vi, ML, 64); }
    pr[r] = vr; pi[r] = vi;
  }
  #pragma unroll
  for (int r = 0; r < 4; r++) {
    re[r] = fmaf(c, re[r],  s * pi[r]);
    im[r] = fmaf(c, im[r], -s * pr[r]);
  }
}

// fold-reduce 8 values across 64 lanes: 10 shuffles. On exit v[0] of lane L holds
// the wave-sum of value w(L) = 4*(L&1) + (L&2) + ((L>>2)&1).
__device__ __forceinline__ void fold_reduce8(float v[8], int L) {
  #pragma unroll
  for (int step = 0; step < 3; step++) {
    int d = 1 << step;
    int half = 4 >> step;
    bool hi = (L & d) != 0;
    #pragma unroll
    for (int w = 0; w < half; w++) {
      float send = hi ? v[w] : v[w + half];
      float recv = __shfl_xor(send, d, 64);
      v[w] = (hi ? v[w + half] : v[w]) + recv;
    }
  }
  v[0] += __shfl_xor(v[0], 8, 64);
  v[0] += __shfl_xor(v[0], 16, 64);
  v[0] += __shfl_xor(v[0], 32, 64);
}

// ---------------- prep: adj/Wg cvt, U-builder (interleaved), G-builder, x transpose ----
// blocks [0,1024): adj cvt; [1024,1088): Wg cvt; [1088,1152): U-builder;
// [1152,1168): G-builder; [1168,5264): x transpose (16,1024,256)->(4096,1024) bf16.
__global__ __launch_bounds__(256)
void prep_kernel(const float* __restrict__ adj, unsigned short* __restrict__ adj_bf,
                 const float* __restrict__ Wg, unsigned short* __restrict__ Wg_bf,
                 const float* __restrict__ qw, unsigned short* __restrict__ Uri,
                 const float* __restrict__ Wpost, _Float16* __restrict__ Gt,
                 const float* __restrict__ x, unsigned short* __restrict__ xT) {
  __shared__ float smem[1056];
  int bid = blockIdx.x, t = threadIdx.x;
  if (bid < 1024) {
    int i = bid * 256 + t;
    float4 v = ((const float4*)adj)[i];
    ushort4 o; o.x = f2bf(v.x); o.y = f2bf(v.y); o.z = f2bf(v.z); o.w = f2bf(v.w);
    ((ushort4*)adj_bf)[i] = o;
  } else if (bid < 1088) {
    int i = (bid - 1024) * 256 + t;
    float4 v = ((const float4*)Wg)[i];
    ushort4 o; o.x = f2bf(v.x); o.y = f2bf(v.y); o.z = f2bf(v.z); o.w = f2bf(v.w);
    ((ushort4*)Wg_bf)[i] = o;
  } else if (bid < 1152) {
    // U-builder: simulate entangler on basis k. CNOT rings deferred (linear maps);
    // layer-2 RX masks = R^-1 e_w; logical index n = R^2 s (rows of R^2 below).
    // Output layout INTERLEAVED by 16-blocks: row (n>>4)*32 + (n&15)      = Ure[n][*]
    //                                         row (n>>4)*32 + 16 + (n&15) = Uim[n][*]
    if (t < 16) { smem[t] = cosf(0.5f * qw[t]); smem[16 + t] = sinf(0.5f * qw[t]); }
    __syncthreads();
    int wv = t >> 6, L = t & 63;
    int k = (bid - 1088) * 4 + wv;
    float re[4], im[4];
    #pragma unroll
    for (int r = 0; r < 4; r++) { re[r] = (r * 64 + L == k) ? 1.f : 0.f; im[r] = 0.f; }
    // layer 1 RX (F = I)
    apply_rx<1, 0>(re, im, smem[0], smem[16]);
    apply_rx<2, 0>(re, im, smem[1], smem[17]);
    apply_rx<4, 0>(re, im, smem[2], smem[18]);
    apply_rx<8, 0>(re, im, smem[3], smem[19]);
    apply_rx<16, 0>(re, im, smem[4], smem[20]);
    apply_rx<32, 0>(re, im, smem[5], smem[21]);
    apply_rx<0, 1>(re, im, smem[6], smem[22]);
    apply_rx<0, 2>(re, im, smem[7], smem[23]);
    // layer 2 RX (F = R): masks R^-1 e_w
    apply_rx<3, 0>(re, im, smem[8], smem[24]);
    apply_rx<6, 0>(re, im, smem[9], smem[25]);
    apply_rx<12, 0>(re, im, smem[10], smem[26]);
    apply_rx<24, 0>(re, im, smem[11], smem[27]);
    apply_rx<48, 0>(re, im, smem[12], smem[28]);
    apply_rx<32, 1>(re, im, smem[13], smem[29]);
    apply_rx<0, 3>(re, im, smem[14], smem[30]);
    apply_rx<3, 2>(re, im, smem[15], smem[31]);
    const int M[8] = {0xAB, 0xFD, 0xFA, 0xF5, 0xEA, 0xD5, 0xAA, 0x55};
    #pragma unroll
    for (int r = 0; r < 4; r++) {
      int n = 0;
      #pragma unroll
      for (int w = 0; w < 8; w++) {
        int bit = (__popc(L & (M[w] & 63)) ^ __popc((r << 6) & M[w])) & 1;
        n |= bit << w;
      }
      int row_re = ((n >> 4) << 5) + (n & 15);
      Uri[(size_t)row_re * 256 + k] = f2bf(re[r]);
      Uri[(size_t)(row_re + 16) * 256 + k] = f2bf(im[r]);
    }
  } else if (bid < 1168) {
    // G-builder: Gt[h][n] = sum_w (-1)^{bit_w(n)} Wpost[h][w]  (f16)
    int tid = (bid - 1152) * 256 + t;   // [0,4096)
    int h = tid >> 4;
    int n0 = (tid & 15) << 4;
    float wv8[8];
    #pragma unroll
    for (int w = 0; w < 8; w++) wv8[w] = Wpost[h * 8 + w];
    #pragma unroll
    for (int j = 0; j < 16; j++) {
      int n = n0 + j;
      float sum = 0.f;
      #pragma unroll
      for (int w = 0; w < 8; w++) sum += ((n >> w) & 1) ? -wv8[w] : wv8[w];
      Gt[h * 256 + n] = (_Float16)sum;
    }
  } else {
    int tb = bid - 1168;
    int jt = tb & 31, ht = (tb >> 5) & 7, bb = tb >> 8;
    int tx = t & 31, ty = t >> 5;
    const float* xb = x + (size_t)bb * 1024 * 256;
    #pragma unroll
    for (int i = 0; i < 4; i++) {
      int j = jt * 32 + ty + i * 8;
      smem[(ty + i * 8) * 33 + tx] = xb[(size_t)j * 256 + ht * 32 + tx];
    }
    __syncthreads();
    unsigned short* xTb = xT + (size_t)bb * 256 * 1024;
    #pragma unroll
    for (int i = 0; i < 4; i++) {
      int h = ht * 32 + ty + i * 8;
      xTb[(size_t)h * 1024 + jt * 32 + tx] = f2bf(smem[tx * 33 + ty + i * 8]);
    }
  }
}

// ---------------- gemm1: C = A * Bt^T, tile 128(M) x 64(N) x 32(K), bf16 out ----
__global__ __launch_bounds__(256)
void gemm1_kernel(const unsigned short* __restrict__ A,
                  const unsigned short* __restrict__ Bt,
                  unsigned short* __restrict__ C,
                  int K, int tilesN, int ldC) {
  __shared__ unsigned short As[128 * 32];
  __shared__ unsigned short Bs[64 * 32];
  int rr  = blockIdx.x;
  int im  = rr / tilesN;
  int in_ = rr % tilesN;
  const unsigned short* Ab  = A  + (long long)im * 128 * K;
  const unsigned short* Btb = Bt + (long long)in_ * 64 * K;

  int t = threadIdx.x;
  int wv = t >> 6, lane = t & 63;
  int wm = wv >> 1, wn = wv & 1;
  int l15 = lane & 15, quad = lane >> 4;
  int row0 = t >> 2, cg = t & 3;

  f32x4 acc[4][2] = {};

  for (int kk = 0; kk < K; kk += 32) {
    __syncthreads();
    #pragma unroll
    for (int q = 0; q < 2; q++) {
      int row = row0 + q * 64;
      async_ld16(Ab + (long long)row * K + kk + cg * 8,
                 &As[(wv * 16 + q * 64) * 32]);
    }
    async_ld16(Btb + (long long)row0 * K + kk + cg * 8,
               &Bs[wv * 16 * 32]);
    __syncthreads();
    bf16x8 af[4], bfr[2];
    #pragma unroll
    for (int mt = 0; mt < 4; mt++)
      af[mt] = *(const bf16x8*)&As[(wm * 64 + mt * 16 + l15) * 32 + quad * 8];
    #pragma unroll
    for (int nt = 0; nt < 2; nt++)
      bfr[nt] = *(const bf16x8*)&Bs[(wn * 32 + nt * 16 + l15) * 32 + quad * 8];
    #pragma unroll
    for (int mt = 0; mt < 4; mt++)
      #pragma unroll
      for (int nt = 0; nt < 2; nt++)
        acc[mt][nt] = __builtin_amdgcn_mfma_f32_16x16x32_bf16(af[mt], bfr[nt], acc[mt][nt], 0, 0, 0);
  }

  int n0 = in_ * 64;
  #pragma unroll
  for (int mt = 0; mt < 4; mt++) {
    #pragma unroll
    for (int nt = 0; nt < 2; nt++) {
      int colg = n0 + wn * 32 + nt * 16 + l15;
      #pragma unroll
      for (int r = 0; r < 4; r++) {
        int rowg = im * 128 + wm * 64 + mt * 16 + quad * 4 + r;
        C[(size_t)rowg * ldC + colg] = f2bf(acc[mt][nt][r]);
      }
    }
  }
}

// ---------------- gemm2p0: g = GELU(xagg @ Wg^T + bg) fused with angles -> P0 ----
// 512 blocks x 256 thr; block owns 32 sample rows x full 256 cols. K=256.
// Wave wv owns g-cols wv*64..+63 in the GEMM; then rows wv*8..+7 for angles/P0.
__global__ __launch_bounds__(256)
void gemm2p0_kernel(const unsigned short* __restrict__ xagg,
                    const unsigned short* __restrict__ Wg,
                    const float* __restrict__ bg,
                    const float* __restrict__ Wpre, const float* __restrict__ bpre,
                    unsigned short* __restrict__ P0) {
  __shared__ unsigned short As[32 * 32];    // 2 KB
  __shared__ unsigned short Bs[256 * 32];   // 16 KB
  __shared__ unsigned short gs[32 * 256];   // 16 KB
  __shared__ float sWpre[2048];             // 8 KB [w][h]

  int t = threadIdx.x;
  int wv = t >> 6, lane = t & 63;
  int l15 = lane & 15, quad = lane >> 4;

  for (int i = t; i < 2048; i += 256) sWpre[i] = Wpre[i];

  const unsigned short* Ab = xagg + (size_t)blockIdx.x * 32 * 256;

  f32x4 acc[2][4] = {};
  for (int kk = 0; kk < 256; kk += 32) {
    __syncthreads();
    if (wv < 2)
      async_ld16(Ab + (size_t)(wv * 16 + (lane >> 2)) * 256 + kk + (lane & 3) * 8,
                 &As[(wv * 16) * 32]);
    #pragma unroll
    for (int rd = 0; rd < 4; rd++) {
      int n = wv * 64 + rd * 16 + (lane >> 2);
      async_ld16(Wg + (size_t)n * 256 + kk + (lane & 3) * 8,
                 &Bs[(wv * 64 + rd * 16) * 32]);
    }
    __syncthreads();
    bf16x8 af[2], bfr[4];
    #pragma unroll
    for (int mt = 0; mt < 2; mt++)
      af[mt] = *(const bf16x8*)&As[(mt * 16 + l15) * 32 + quad * 8];
    #pragma unroll
    for (int nt = 0; nt < 4; nt++)
      bfr[nt] = *(const bf16x8*)&Bs[(wv * 64 + nt * 16 + l15) * 32 + quad * 8];
    #pragma unroll
    for (int mt = 0; mt < 2; mt++)
      #pragma unroll
      for (int nt = 0; nt < 4; nt++)
        acc[mt][nt] = __builtin_amdgcn_mfma_f32_16x16x32_bf16(af[mt], bfr[nt], acc[mt][nt], 0, 0, 0);
  }

  // epilogue: bias + GELU -> gs (bf16)
  #pragma unroll
  for (int mt = 0; mt < 2; mt++) {
    #pragma unroll
    for (int nt = 0; nt < 4; nt++) {
      int col = wv * 64 + nt * 16 + l15;
      float bgl = bg[col];
      #pragma unroll
      for (int r = 0; r < 4; r++) {
        int row = mt * 16 + quad * 4 + r;
        float v = acc[mt][nt][r] + bgl;
        v = 0.5f * v * (1.0f + fast_erf(v * 0.7071067811865475f));
        gs[row * 256 + col] = f2bf(v);
      }
    }
  }
  __syncthreads();

  // angles + RY product state: wave wv handles rows wv*8..+7
  #pragma unroll
  for (int rr = 0; rr < 8; rr++) {
    int row = wv * 8 + rr;
    ushort4 gu = *(const ushort4*)&gs[row * 256 + 4 * lane];
    float g0 = bf2f(gu.x), g1 = bf2f(gu.y), g2 = bf2f(gu.z), g3 = bf2f(gu.w);
    float ang[8];
    #pragma unroll
    for (int w = 0; w < 8; w++) {
      float4 wp = *(const float4*)&sWpre[w * 256 + 4 * lane];
      float a = g0 * wp.x;
      a = fmaf(g1, wp.y, a);
      a = fmaf(g2, wp.z, a);
      a = fmaf(g3, wp.w, a);
      ang[w] = a;
    }
    fold_reduce8(ang, lane);
    float angf[8];
    #pragma unroll
    for (int w = 0; w < 8; w++) {
      int src = ((w >> 2) & 1) | (w & 2) | ((w & 1) << 2);
      angf[w] = __shfl(ang[0], src, 64);
    }
    float cw[8], sw[8];
    #pragma unroll
    for (int w = 0; w < 8; w++) {
      float th = (0.5f * PI_F) * fast_tanh(angf[w] + bpre[w]);
      cw[w] = __cosf(th); sw[w] = __sinf(th);
    }
    // amp index n = 4*lane + j : bits 0,1 = j ; bits 2..7 = lane bits 0..5
    float pl = 1.f;
    #pragma unroll
    for (int bbit = 0; bbit < 6; bbit++) pl *= ((lane >> bbit) & 1) ? sw[bbit + 2] : cw[bbit + 2];
    ushort4 o;
    o.x = f2bf(pl * cw[0] * cw[1]);
    o.y = f2bf(pl * sw[0] * cw[1]);
    o.z = f2bf(pl * cw[0] * sw[1]);
    o.w = f2bf(pl * sw[0] * sw[1]);
    size_t srow = (size_t)blockIdx.x * 32 + row;
    *(ushort4*)(P0 + srow * 256 + 4 * lane) = o;
  }
}

// ---------------- qtail: S = P0 @ Uri^T -> T = |S|^2 (LDS) -> out = T @ Gt^T + bpost ----
// 512 blocks x 256 thr; block owns 32 samples, full width.
// Stage1: wave wv owns S-cols wv*128..+127 (Uri interleaved: pair (nt=2p,2p+1) = re/im of
//   T-col n = (wv*4+p)*16 + l15). T written to LDS panels Ts[kb][row][32] f16.
// Stage2: out(32x256) = Ts @ Gt^T; wave wv owns out-cols wv*64..+63; store fp32 with
//   row un-permute s = i*16+b -> b*1024+i.
__global__ __launch_bounds__(256)
void qtail_kernel(const unsigned short* __restrict__ P0,
                  const unsigned short* __restrict__ Uri,
                  const _Float16* __restrict__ Gt,
                  const float* __restrict__ bpost,
                  float* __restrict__ out) {
  __shared__ unsigned short As[32 * 32];     // 2 KB
  __shared__ unsigned short Bs[512 * 32];    // 32 KB (stage2 reuses first 16 KB)
  __shared__ _Float16 Ts[8 * 32 * 32];       // 16 KB, [kb][row][n%32]

  int t = threadIdx.x;
  int wv = t >> 6, lane = t & 63;
  int l15 = lane & 15, quad = lane >> 4;

  const unsigned short* Ab = P0 + (size_t)blockIdx.x * 32 * 256;

  // ---- stage 1: S = P0 @ Uri^T ----
  f32x4 acc[2][8] = {};
  for (int kk = 0; kk < 256; kk += 32) {
    __syncthreads();
    if (wv < 2)
      async_ld16(Ab + (size_t)(wv * 16 + (lane >> 2)) * 256 + kk + (lane & 3) * 8,
                 &As[(wv * 16) * 32]);
    #pragma unroll
    for (int rd = 0; rd < 8; rd++) {
      int n = wv * 128 + rd * 16 + (lane >> 2);
      async_ld16(Uri + (size_t)n * 256 + kk + (lane & 3) * 8,
                 &Bs[(wv * 128 + rd * 16) * 32]);
    }
    __syncthreads();
    bf16x8 af[2], bfr[8];
    #pragma unroll
    for (int mt = 0; mt < 2; mt++)
      af[mt] = *(const bf16x8*)&As[(mt * 16 + l15) * 32 + quad * 8];
    #pragma unroll
    for (int nt = 0; nt < 8; nt++)
      bfr[nt] = *(const bf16x8*)&Bs[(wv * 128 + nt * 16 + l15) * 32 + quad * 8];
    #pragma unroll
    for (int mt = 0; mt < 2; mt++)
      #pragma unroll
      for (int nt = 0; nt < 8; nt++)
        acc[mt][nt] = __builtin_amdgcn_mfma_f32_16x16x32_bf16(af[mt], bfr[nt], acc[mt][nt], 0, 0, 0);
  }

  // T = Sre^2 + Sim^2 -> Ts panels
  #pragma unroll
  for (int mt = 0; mt < 2; mt++) {
    #pragma unroll
    for (int p = 0; p < 4; p++) {
      int kb = wv * 2 + (p >> 1);
      int cip = (p & 1) * 16 + l15;
      #pragma unroll
      for (int r = 0; r < 4; r++) {
        int row = mt * 16 + quad * 4 + r;
        float tre = acc[mt][2 * p][r], tim = acc[mt][2 * p + 1][r];
        Ts[kb * 1024 + row * 32 + cip] = (_Float16)(tre * tre + tim * tim);
      }
    }
  }

  // ---- stage 2: out = Ts @ Gt^T + bpost ----
  f32x4 acc2[2][4] = {};
  for (int kk = 0; kk < 256; kk += 32) {
    __syncthreads();   // first iter: Ts complete & Bs reads done before overwrite
    #pragma unroll
    for (int rd = 0; rd < 4; rd++) {
      int h = wv * 64 + rd * 16 + (lane >> 2);
      async_ld16((const unsigned short*)Gt + (size_t)h * 256 + kk + (lane & 3) * 8,
                 &Bs[(wv * 64 + rd * 16) * 32]);
    }
    __syncthreads();
    f16x8 af[2], bfr[4];
    #pragma unroll
    for (int mt = 0; mt < 2; mt++)
      af[mt] = *(const f16x8*)&Ts[(kk >> 5) * 1024 + (mt * 16 + l15) * 32 + quad * 8];
    #pragma unroll
    for (int nt = 0; nt < 4; nt++)
      bfr[nt] = *(const f16x8*)&Bs[(wv * 64 + nt * 16 + l15) * 32 + quad * 8];
    #pragma unroll
    for (int mt = 0; mt < 2; mt++)
      #pragma unroll
      for (int nt = 0; nt < 4; nt++)
        acc2[mt][nt] = __builtin_amdgcn_mfma_f32_16x16x32_f16(af[mt], bfr[nt], acc2[mt][nt], 0, 0, 0);
  }

  // epilogue: bias + fp32 store with sample un-permute (s = i*16+b -> b*1024+i)
  #pragma unroll
  for (int mt = 0; mt < 2; mt++) {
    #pragma unroll
    for (int nt = 0; nt < 4; nt++) {
      int col = wv * 64 + nt * 16 + l15;
      float bp = bpost[col];
      #pragma unroll
      for (int r = 0; r < 4; r++) {
        int row = mt * 16 + quad * 4 + r;
        int s = blockIdx.x * 32 + row;
        int orow = (s & 15) * 1024 + (s >> 4);
        out[(size_t)orow * 256 + col] = acc2[mt][nt][r] + bp;
      }
    }
  }
}

// ---------------- host launch ----------------
extern "C" void kernel_launch(void* const* d_in, const int* in_sizes, int n_in,
                              void* d_out, int out_size, void* d_ws, size_t ws_size,
                              hipStream_t stream) {
  const float* x     = (const float*)d_in[0];  // (16,1024,256)
  const float* adj   = (const float*)d_in[1];  // (1024,1024)
  const float* Wg    = (const float*)d_in[2];  // (256,256)
  const float* bg    = (const float*)d_in[3];  // (256,)
  const float* Wpre  = (const float*)d_in[4];  // (8,256)
  const float* bpre  = (const float*)d_in[5];  // (8,)
  const float* qw    = (const float*)d_in[6];  // (2,8)
  const float* Wpost = (const float*)d_in[7];  // (256,8)
  const float* bpost = (const float*)d_in[8];  // (256,)
  float* out = (float*)d_out;                  // (16,1024,256)

  char* ws = (char*)d_ws;
  unsigned short* adj_bf  = (unsigned short*)(ws + 0);          // 2 MiB
  unsigned short* Wg_bf   = (unsigned short*)(ws + 2097152);    // 128 KiB
  unsigned short* xT_bf   = (unsigned short*)(ws + 2228224);    // 8 MiB  (4096 x 1024)
  unsigned short* xagg_bf = (unsigned short*)(ws + 10616832);   // 8 MiB  (1024 x 4096 = 16384 x 256)
  unsigned short* P0      = (unsigned short*)(ws + 19005440);   // 8 MiB  (16384 x 256)
  unsigned short* Uri     = (unsigned short*)(ws + 27394048);   // 256 KiB (512 x 256)
  _Float16*       Gt      = (_Float16*)(ws + 27656192);         // 128 KiB (256 x 256)

  // 1) prep: adj/Wg cvt + U-builder (interleaved) + G-builder + x transpose
  prep_kernel<<<5264, 256, 0, stream>>>(adj, adj_bf, Wg, Wg_bf, qw, Uri,
                                        Wpost, Gt, x, xT_bf);

  // 2) xagg = adj @ X'  (1024 x 4096 x 1024) -> bf16; rows of the 16384x256 view are s=i*16+b
  gemm1_kernel<<<512, 256, 0, stream>>>(adj_bf, xT_bf, xagg_bf, 1024, 64, 4096);

  // 3) g = GELU(xagg @ Wg^T + bg) fused with angles -> P0 (bf16, logical basis)
  gemm2p0_kernel<<<512, 256, 0, stream>>>(xagg_bf, Wg_bf, bg, Wpre, bpre, P0);

  // 4) S-GEMM + |S|^2 + out-projection + un-permute
  qtail_kernel<<<512, 256, 0, stream>>>(P0, Uri, Gt, bpost, out);
}

// Round 9
// 147.200 us; speedup vs baseline: 1.0877x; 1.0514x over previous
//
#include <hip/hip_runtime.h>
#include <math.h>

typedef __attribute__((ext_vector_type(8))) short bf16x8;
typedef _Float16 f16x8 __attribute__((ext_vector_type(8)));
typedef __attribute__((ext_vector_type(4))) float f32x4;

#define PI_F 3.14159265358979323846f

__device__ __forceinline__ unsigned short f2bf(float f) {
  unsigned int u = __float_as_uint(f);
  u += 0x7FFFu + ((u >> 16) & 1u);   // RNE to bf16
  return (unsigned short)(u >> 16);
}

__device__ __forceinline__ float bf2f(unsigned short u) {
  return __uint_as_float(((unsigned int)u) << 16);
}

__device__ __forceinline__ void async_ld16(const unsigned short* g, unsigned short* l) {
  __builtin_amdgcn_global_load_lds(
      (const __attribute__((address_space(1))) void*)g,
      (__attribute__((address_space(3))) void*)l,
      16, 0, 0);
}

// fast erf, A&S 7.1.26, |err| <= 1.5e-7 absolute
__device__ __forceinline__ float fast_erf(float x) {
  float a = fabsf(x);
  float t = 1.0f / fmaf(0.3275911f, a, 1.0f);
  float p = t * fmaf(t, fmaf(t, fmaf(t, fmaf(t, 1.061405429f, -1.453152027f),
                                     1.421413741f), -0.284496736f), 0.254829592f);
  float e = __expf(-a * a);
  float r = 1.0f - p * e;
  return copysignf(r, x);
}

__device__ __forceinline__ float fast_tanh(float a) {
  float e = __expf(2.0f * a);
  return 1.0f - 2.0f / (e + 1.0f);
}

// RX on stored basis: XOR-pair (lane-mask ML, register-mask MR); RX matrix symmetric.
template<int ML, int MR>
__device__ __forceinline__ void apply_rx(float re[4], float im[4], float c, float s) {
  float pr[4], pi[4];
  #pragma unroll
  for (int r = 0; r < 4; r++) {
    float vr = re[r ^ MR], vi = im[r ^ MR];
    if (ML) { vr = __shfl_xor(vr, ML, 64); vi = __shfl_xor(vi, ML, 64); }
    pr[r] = vr; pi[r] = vi;
  }
  #pragma unroll
  for (int r = 0; r < 4; r++) {
    re[r] = fmaf(c, re[r],  s * pi[r]);
    im[r] = fmaf(c, im[r], -s * pr[r]);
  }
}

// fold-reduce 8 values across 64 lanes: 10 shuffles. On exit v[0] of lane L holds
// the wave-sum of value w(L) = 4*(L&1) + (L&2) + ((L>>2)&1).
__device__ __forceinline__ void fold_reduce8(float v[8], int L) {
  #pragma unroll
  for (int step = 0; step < 3; step++) {
    int d = 1 << step;
    int half = 4 >> step;
    bool hi = (L & d) != 0;
    #pragma unroll
    for (int w = 0; w < half; w++) {
      float send = hi ? v[w] : v[w + half];
      float recv = __shfl_xor(send, d, 64);
      v[w] = (hi ? v[w + half] : v[w]) + recv;
    }
  }
  v[0] += __shfl_xor(v[0], 8, 64);
  v[0] += __shfl_xor(v[0], 16, 64);
  v[0] += __shfl_xor(v[0], 32, 64);
}

// ---------------- prep: adj/Wg cvt, U-builder (interleaved), G-builder, x transpose ----
// blocks [0,1024): adj cvt; [1024,1088): Wg cvt; [1088,1152): U-builder;
// [1152,1168): G-builder; [1168,5264): x transpose (16,1024,256)->(4096,1024) bf16.
__global__ __launch_bounds__(256)
void prep_kernel(const float* __restrict__ adj, unsigned short* __restrict__ adj_bf,
                 const float* __restrict__ Wg, unsigned short* __restrict__ Wg_bf,
                 const float* __restrict__ qw, unsigned short* __restrict__ Uri,
                 const float* __restrict__ Wpost, _Float16* __restrict__ Gt,
                 const float* __restrict__ x, unsigned short* __restrict__ xT) {
  __shared__ float smem[1056];
  int bid = blockIdx.x, t = threadIdx.x;
  if (bid < 1024) {
    int i = bid * 256 + t;
    float4 v = ((const float4*)adj)[i];
    ushort4 o; o.x = f2bf(v.x); o.y = f2bf(v.y); o.z = f2bf(v.z); o.w = f2bf(v.w);
    ((ushort4*)adj_bf)[i] = o;
  } else if (bid < 1088) {
    int i = (bid - 1024) * 256 + t;
    float4 v = ((const float4*)Wg)[i];
    ushort4 o; o.x = f2bf(v.x); o.y = f2bf(v.y); o.z = f2bf(v.z); o.w = f2bf(v.w);
    ((ushort4*)Wg_bf)[i] = o;
  } else if (bid < 1152) {
    // U-builder: simulate entangler on basis k. CNOT rings deferred (linear maps);
    // layer-2 RX masks = R^-1 e_w; logical index n = R^2 s (rows of R^2 below).
    // Output layout INTERLEAVED by 16-blocks: row (n>>4)*32 + (n&15)      = Ure[n][*]
    //                                         row (n>>4)*32 + 16 + (n&15) = Uim[n][*]
    if (t < 16) { smem[t] = cosf(0.5f * qw[t]); smem[16 + t] = sinf(0.5f * qw[t]); }
    __syncthreads();
    int wv = t >> 6, L = t & 63;
    int k = (bid - 1088) * 4 + wv;
    float re[4], im[4];
    #pragma unroll
    for (int r = 0; r < 4; r++) { re[r] = (r * 64 + L == k) ? 1.f : 0.f; im[r] = 0.f; }
    // layer 1 RX (F = I)
    apply_rx<1, 0>(re, im, smem[0], smem[16]);
    apply_rx<2, 0>(re, im, smem[1], smem[17]);
    apply_rx<4, 0>(re, im, smem[2], smem[18]);
    apply_rx<8, 0>(re, im, smem[3], smem[19]);
    apply_rx<16, 0>(re, im, smem[4], smem[20]);
    apply_rx<32, 0>(re, im, smem[5], smem[21]);
    apply_rx<0, 1>(re, im, smem[6], smem[22]);
    apply_rx<0, 2>(re, im, smem[7], smem[23]);
    // layer 2 RX (F = R): masks R^-1 e_w
    apply_rx<3, 0>(re, im, smem[8], smem[24]);
    apply_rx<6, 0>(re, im, smem[9], smem[25]);
    apply_rx<12, 0>(re, im, smem[10], smem[26]);
    apply_rx<24, 0>(re, im, smem[11], smem[27]);
    apply_rx<48, 0>(re, im, smem[12], smem[28]);
    apply_rx<32, 1>(re, im, smem[13], smem[29]);
    apply_rx<0, 3>(re, im, smem[14], smem[30]);
    apply_rx<3, 2>(re, im, smem[15], smem[31]);
    const int M[8] = {0xAB, 0xFD, 0xFA, 0xF5, 0xEA, 0xD5, 0xAA, 0x55};
    #pragma unroll
    for (int r = 0; r < 4; r++) {
      int n = 0;
      #pragma unroll
      for (int w = 0; w < 8; w++) {
        int bit = (__popc(L & (M[w] & 63)) ^ __popc((r << 6) & M[w])) & 1;
        n |= bit << w;
      }
      int row_re = ((n >> 4) << 5) + (n & 15);
      Uri[(size_t)row_re * 256 + k] = f2bf(re[r]);
      Uri[(size_t)(row_re + 16) * 256 + k] = f2bf(im[r]);
    }
  } else if (bid < 1168) {
    // G-builder: Gt[h][n] = sum_w (-1)^{bit_w(n)} Wpost[h][w]  (f16)
    int tid = (bid - 1152) * 256 + t;   // [0,4096)
    int h = tid >> 4;
    int n0 = (tid & 15) << 4;
    float wv8[8];
    #pragma unroll
    for (int w = 0; w < 8; w++) wv8[w] = Wpost[h * 8 + w];
    #pragma unroll
    for (int j = 0; j < 16; j++) {
      int n = n0 + j;
      float sum = 0.f;
      #pragma unroll
      for (int w = 0; w < 8; w++) sum += ((n >> w) & 1) ? -wv8[w] : wv8[w];
      Gt[h * 256 + n] = (_Float16)sum;
    }
  } else {
    int tb = bid - 1168;
    int jt = tb & 31, ht = (tb >> 5) & 7, bb = tb >> 8;
    int tx = t & 31, ty = t >> 5;
    const float* xb = x + (size_t)bb * 1024 * 256;
    #pragma unroll
    for (int i = 0; i < 4; i++) {
      int j = jt * 32 + ty + i * 8;
      smem[(ty + i * 8) * 33 + tx] = xb[(size_t)j * 256 + ht * 32 + tx];
    }
    __syncthreads();
    unsigned short* xTb = xT + (size_t)bb * 256 * 1024;
    #pragma unroll
    for (int i = 0; i < 4; i++) {
      int h = ht * 32 + ty + i * 8;
      xTb[(size_t)h * 1024 + jt * 32 + tx] = f2bf(smem[tx * 33 + ty + i * 8]);
    }
  }
}

// ---------------- gemm1: C = A * Bt^T, tile 128(M) x 64(N), BK=64 (two 32-k panels) ----
// Half the barriers of BK=32 at the same staging-instruction count.
__global__ __launch_bounds__(256)
void gemm1_kernel(const unsigned short* __restrict__ A,
                  const unsigned short* __restrict__ Bt,
                  unsigned short* __restrict__ C,
                  int K, int tilesN, int ldC) {
  __shared__ unsigned short As[2 * 128 * 32];   // 16 KB, [kb][row][32]
  __shared__ unsigned short Bs[2 * 64 * 32];    // 8 KB,  [kb][row][32]
  int rr  = blockIdx.x;
  int im  = rr / tilesN;
  int in_ = rr % tilesN;
  const unsigned short* Ab  = A  + (long long)im * 128 * K;
  const unsigned short* Btb = Bt + (long long)in_ * 64 * K;

  int t = threadIdx.x;
  int wv = t >> 6, lane = t & 63;
  int wm = wv >> 1, wn = wv & 1;
  int l15 = lane & 15, quad = lane >> 4;

  f32x4 acc[4][2] = {};

  for (int kk = 0; kk < K; kk += 64) {
    __syncthreads();
    #pragma unroll
    for (int kb = 0; kb < 2; kb++) {
      #pragma unroll
      for (int q = 0; q < 2; q++) {
        int ch = q * 256 + t;                 // 0..511 -> row = ch>>2, col16 = ch&3
        async_ld16(Ab + (long long)(ch >> 2) * K + kk + kb * 32 + (ch & 3) * 8,
                   &As[kb * 4096 + ch * 8]);
      }
      {
        int ch = t;                           // 0..255 -> row = ch>>2
        async_ld16(Btb + (long long)(ch >> 2) * K + kk + kb * 32 + (ch & 3) * 8,
                   &Bs[kb * 2048 + ch * 8]);
      }
    }
    __syncthreads();
    #pragma unroll
    for (int kb = 0; kb < 2; kb++) {
      bf16x8 af[4], bfr[2];
      #pragma unroll
      for (int mt = 0; mt < 4; mt++)
        af[mt] = *(const bf16x8*)&As[kb * 4096 + (wm * 64 + mt * 16 + l15) * 32 + quad * 8];
      #pragma unroll
      for (int nt = 0; nt < 2; nt++)
        bfr[nt] = *(const bf16x8*)&Bs[kb * 2048 + (wn * 32 + nt * 16 + l15) * 32 + quad * 8];
      #pragma unroll
      for (int mt = 0; mt < 4; mt++)
        #pragma unroll
        for (int nt = 0; nt < 2; nt++)
          acc[mt][nt] = __builtin_amdgcn_mfma_f32_16x16x32_bf16(af[mt], bfr[nt], acc[mt][nt], 0, 0, 0);
    }
  }

  int n0 = in_ * 64;
  #pragma unroll
  for (int mt = 0; mt < 4; mt++) {
    #pragma unroll
    for (int nt = 0; nt < 2; nt++) {
      int colg = n0 + wn * 32 + nt * 16 + l15;
      #pragma unroll
      for (int r = 0; r < 4; r++) {
        int rowg = im * 128 + wm * 64 + mt * 16 + quad * 4 + r;
        C[(size_t)rowg * ldC + colg] = f2bf(acc[mt][nt][r]);
      }
    }
  }
}

// ---------------- qfused: g-GEMM + GELU + angles + P0 + S-GEMM + |S|^2 + out-GEMM ----
// 512 blocks x 256 thr; block owns 32 samples, everything after xagg stays in LDS.
// LDS arena (74 KB -> 2 blocks/CU):
//   As 2K | Bs 32K (Wg 16K / Uri 32K / Gt 16K) | gs~Ts 16K | P0s 16K | sWpre 8K
__global__ __launch_bounds__(256)
void qfused_kernel(const unsigned short* __restrict__ xagg,
                   const unsigned short* __restrict__ Wg,
                   const float* __restrict__ bg,
                   const float* __restrict__ Wpre, const float* __restrict__ bpre,
                   const unsigned short* __restrict__ Uri,
                   const _Float16* __restrict__ Gt,
                   const float* __restrict__ bpost,
                   float* __restrict__ out) {
  __shared__ __align__(16) char smemraw[75776];
  unsigned short* As    = (unsigned short*)smemraw;            // 2 KB
  unsigned short* Bs    = (unsigned short*)(smemraw + 2048);   // 32 KB
  unsigned short* gs    = (unsigned short*)(smemraw + 34816);  // 16 KB (bf16 g)
  _Float16*       Ts    = (_Float16*)(smemraw + 34816);        //   (reused as f16 T panels)
  unsigned short* P0s   = (unsigned short*)(smemraw + 51200);  // 16 KB panels [kb][row][32]
  float*          sWpre = (float*)(smemraw + 67584);           // 8 KB [w][h]

  int t = threadIdx.x;
  int wv = t >> 6, lane = t & 63;
  int l15 = lane & 15, quad = lane >> 4;

  for (int i = t; i < 2048; i += 256) sWpre[i] = Wpre[i];

  const unsigned short* Ab = xagg + (size_t)blockIdx.x * 32 * 256;

  // ---- stage A: g = GELU(xagg @ Wg^T + bg), wave wv owns cols wv*64..+63 ----
  f32x4 acc[2][4] = {};
  for (int kk = 0; kk < 256; kk += 32) {
    __syncthreads();
    if (wv < 2)
      async_ld16(Ab + (size_t)(wv * 16 + (lane >> 2)) * 256 + kk + (lane & 3) * 8,
                 &As[(wv * 16) * 32]);
    #pragma unroll
    for (int rd = 0; rd < 4; rd++) {
      int n = wv * 64 + rd * 16 + (lane >> 2);
      async_ld16(Wg + (size_t)n * 256 + kk + (lane & 3) * 8,
                 &Bs[(wv * 64 + rd * 16) * 32]);
    }
    __syncthreads();
    bf16x8 af[2], bfr[4];
    #pragma unroll
    for (int mt = 0; mt < 2; mt++)
      af[mt] = *(const bf16x8*)&As[(mt * 16 + l15) * 32 + quad * 8];
    #pragma unroll
    for (int nt = 0; nt < 4; nt++)
      bfr[nt] = *(const bf16x8*)&Bs[(wv * 64 + nt * 16 + l15) * 32 + quad * 8];
    #pragma unroll
    for (int mt = 0; mt < 2; mt++)
      #pragma unroll
      for (int nt = 0; nt < 4; nt++)
        acc[mt][nt] = __builtin_amdgcn_mfma_f32_16x16x32_bf16(af[mt], bfr[nt], acc[mt][nt], 0, 0, 0);
  }
  #pragma unroll
  for (int mt = 0; mt < 2; mt++) {
    #pragma unroll
    for (int nt = 0; nt < 4; nt++) {
      int col = wv * 64 + nt * 16 + l15;
      float bgl = bg[col];
      #pragma unroll
      for (int r = 0; r < 4; r++) {
        int row = mt * 16 + quad * 4 + r;
        float v = acc[mt][nt][r] + bgl;
        v = 0.5f * v * (1.0f + fast_erf(v * 0.7071067811865475f));
        gs[row * 256 + col] = f2bf(v);
      }
    }
  }
  __syncthreads();   // gs complete

  // ---- angles + RY product state -> P0s panels; wave wv owns rows wv*8..+7 ----
  #pragma unroll
  for (int rr = 0; rr < 8; rr++) {
    int row = wv * 8 + rr;
    ushort4 gu = *(const ushort4*)&gs[row * 256 + 4 * lane];
    float g0 = bf2f(gu.x), g1 = bf2f(gu.y), g2 = bf2f(gu.z), g3 = bf2f(gu.w);
    float ang[8];
    #pragma unroll
    for (int w = 0; w < 8; w++) {
      float4 wp = *(const float4*)&sWpre[w * 256 + 4 * lane];
      float a = g0 * wp.x;
      a = fmaf(g1, wp.y, a);
      a = fmaf(g2, wp.z, a);
      a = fmaf(g3, wp.w, a);
      ang[w] = a;
    }
    fold_reduce8(ang, lane);
    float angf[8];
    #pragma unroll
    for (int w = 0; w < 8; w++) {
      int src = ((w >> 2) & 1) | (w & 2) | ((w & 1) << 2);
      angf[w] = __shfl(ang[0], src, 64);
    }
    float cw[8], sw[8];
    #pragma unroll
    for (int w = 0; w < 8; w++) {
      float th = (0.5f * PI_F) * fast_tanh(angf[w] + bpre[w]);
      cw[w] = __cosf(th); sw[w] = __sinf(th);
    }
    // amp index n = 4*lane + j : bits 0,1 = j ; bits 2..7 = lane bits 0..5
    float pl = 1.f;
    #pragma unroll
    for (int bbit = 0; bbit < 6; bbit++) pl *= ((lane >> bbit) & 1) ? sw[bbit + 2] : cw[bbit + 2];
    ushort4 o;
    o.x = f2bf(pl * cw[0] * cw[1]);
    o.y = f2bf(pl * sw[0] * cw[1]);
    o.z = f2bf(pl * cw[0] * sw[1]);
    o.w = f2bf(pl * sw[0] * sw[1]);
    *(ushort4*)&P0s[(lane >> 3) * 1024 + row * 32 + 4 * (lane & 7)] = o;
  }

  // ---- stage B: S = P0s @ Uri^T, wave wv owns S-cols wv*128..+127 ----
  // Uri interleaved: nt pair (2p, 2p+1) = re/im of T-col n = (wv*4+p)*16 + l15.
  f32x4 acc1[2][8] = {};
  for (int kk = 0; kk < 256; kk += 32) {
    __syncthreads();   // first iter: P0s complete + last Wg frag reads done
    #pragma unroll
    for (int rd = 0; rd < 8; rd++) {
      int n = wv * 128 + rd * 16 + (lane >> 2);
      async_ld16(Uri + (size_t)n * 256 + kk + (lane & 3) * 8,
                 &Bs[(wv * 128 + rd * 16) * 32]);
    }
    __syncthreads();
    bf16x8 af[2], bfr[8];
    #pragma unroll
    for (int mt = 0; mt < 2; mt++)
      af[mt] = *(const bf16x8*)&P0s[(kk >> 5) * 1024 + (mt * 16 + l15) * 32 + quad * 8];
    #pragma unroll
    for (int nt = 0; nt < 8; nt++)
      bfr[nt] = *(const bf16x8*)&Bs[(wv * 128 + nt * 16 + l15) * 32 + quad * 8];
    #pragma unroll
    for (int mt = 0; mt < 2; mt++)
      #pragma unroll
      for (int nt = 0; nt < 8; nt++)
        acc1[mt][nt] = __builtin_amdgcn_mfma_f32_16x16x32_bf16(af[mt], bfr[nt], acc1[mt][nt], 0, 0, 0);
  }

  // T = Sre^2 + Sim^2 -> Ts panels (reuses gs space; gs reads ended before stage B)
  #pragma unroll
  for (int mt = 0; mt < 2; mt++) {
    #pragma unroll
    for (int p = 0; p < 4; p++) {
      int kb = wv * 2 + (p >> 1);
      int cip = (p & 1) * 16 + l15;
      #pragma unroll
      for (int r = 0; r < 4; r++) {
        int row = mt * 16 + quad * 4 + r;
        float tre = acc1[mt][2 * p][r], tim = acc1[mt][2 * p + 1][r];
        Ts[kb * 1024 + row * 32 + cip] = (_Float16)(tre * tre + tim * tim);
      }
    }
  }

  // ---- stage C: out = Ts @ Gt^T + bpost, wave wv owns out-cols wv*64..+63 ----
  f32x4 acc2[2][4] = {};
  for (int kk = 0; kk < 256; kk += 32) {
    __syncthreads();   // first iter: Ts complete + Uri frag reads done
    #pragma unroll
    for (int rd = 0; rd < 4; rd++) {
      int h = wv * 64 + rd * 16 + (lane >> 2);
      async_ld16((const unsigned short*)Gt + (size_t)h * 256 + kk + (lane & 3) * 8,
                 &Bs[(wv * 64 + rd * 16) * 32]);
    }
    __syncthreads();
    f16x8 af[2], bfr[4];
    #pragma unroll
    for (int mt = 0; mt < 2; mt++)
      af[mt] = *(const f16x8*)&Ts[(kk >> 5) * 1024 + (mt * 16 + l15) * 32 + quad * 8];
    #pragma unroll
    for (int nt = 0; nt < 4; nt++)
      bfr[nt] = *(const f16x8*)&Bs[(wv * 64 + nt * 16 + l15) * 32 + quad * 8];
    #pragma unroll
    for (int mt = 0; mt < 2; mt++)
      #pragma unroll
      for (int nt = 0; nt < 4; nt++)
        acc2[mt][nt] = __builtin_amdgcn_mfma_f32_16x16x32_f16(af[mt], bfr[nt], acc2[mt][nt], 0, 0, 0);
  }

  // epilogue: bias + fp32 store with sample un-permute (s = i*16+b -> b*1024+i)
  #pragma unroll
  for (int mt = 0; mt < 2; mt++) {
    #pragma unroll
    for (int nt = 0; nt < 4; nt++) {
      int col = wv * 64 + nt * 16 + l15;
      float bp = bpost[col];
      #pragma unroll
      for (int r = 0; r < 4; r++) {
        int row = mt * 16 + quad * 4 + r;
        int s = blockIdx.x * 32 + row;
        int orow = (s & 15) * 1024 + (s >> 4);
        out[(size_t)orow * 256 + col] = acc2[mt][nt][r] + bp;
      }
    }
  }
}

// ---------------- host launch ----------------
extern "C" void kernel_launch(void* const* d_in, const int* in_sizes, int n_in,
                              void* d_out, int out_size, void* d_ws, size_t ws_size,
                              hipStream_t stream) {
  const float* x     = (const float*)d_in[0];  // (16,1024,256)
  const float* adj   = (const float*)d_in[1];  // (1024,1024)
  const float* Wg    = (const float*)d_in[2];  // (256,256)
  const float* bg    = (const float*)d_in[3];  // (256,)
  const float* Wpre  = (const float*)d_in[4];  // (8,256)
  const float* bpre  = (const float*)d_in[5];  // (8,)
  const float* qw    = (const float*)d_in[6];  // (2,8)
  const float* Wpost = (const float*)d_in[7];  // (256,8)
  const float* bpost = (const float*)d_in[8];  // (256,)
  float* out = (float*)d_out;                  // (16,1024,256)

  char* ws = (char*)d_ws;
  unsigned short* adj_bf  = (unsigned short*)(ws + 0);          // 2 MiB
  unsigned short* Wg_bf   = (unsigned short*)(ws + 2097152);    // 128 KiB
  unsigned short* xT_bf   = (unsigned short*)(ws + 2228224);    // 8 MiB  (4096 x 1024)
  unsigned short* xagg_bf = (unsigned short*)(ws + 10616832);   // 8 MiB  (16384 x 256 view)
  unsigned short* Uri     = (unsigned short*)(ws + 19005440);   // 256 KiB (512 x 256)
  _Float16*       Gt      = (_Float16*)(ws + 19267584);         // 128 KiB (256 x 256)

  // 1) prep: adj/Wg cvt + U-builder (interleaved) + G-builder + x transpose
  prep_kernel<<<5264, 256, 0, stream>>>(adj, adj_bf, Wg, Wg_bf, qw, Uri,
                                        Wpost, Gt, x, xT_bf);

  // 2) xagg = adj @ X'  (1024 x 4096 x 1024, BK=64) -> bf16; 16384x256 rows are s=i*16+b
  gemm1_kernel<<<512, 256, 0, stream>>>(adj_bf, xT_bf, xagg_bf, 1024, 64, 4096);

  // 3) fused: g-GEMM + GELU + angles + P0 (LDS) + S-GEMM + |S|^2 + out-GEMM + un-permute
  qfused_kernel<<<512, 256, 0, stream>>>(xagg_bf, Wg_bf, bg, Wpre, bpre, Uri, Gt, bpost, out);
}